// Round 1
// baseline (1044.692 us; speedup 1.0000x reference)
//
#include <hip/hip_runtime.h>
#include <hip/hip_bf16.h>

#define B_SZ   1024
#define HIDN   256
#define NSTAGE 6
#define NPTS   36
#define HGT    20
#define WID    20
#define HW     400

// ---------------------------------------------------------------------------
// Prepass: fmp[b][hw][c] = fm[b][c][hw] + pos[b][c][hw]   (transpose to C-major)
// grid (HW/16, B), 256 threads. LDS-tiled transpose, both sides coalesced.
// ---------------------------------------------------------------------------
__global__ __launch_bounds__(256) void prepass_kernel(
    const float* __restrict__ fm, const float* __restrict__ pos,
    float* __restrict__ fmp)
{
    const int b  = blockIdx.y;
    const int h0 = blockIdx.x * 16;
    __shared__ float tile[256][17];
    const int t  = threadIdx.x;
    const int ci = t >> 4;     // 0..15
    const int i  = t & 15;     // 0..15
    const size_t baseIn = (size_t)b * HIDN * HW;
    #pragma unroll
    for (int cb = 0; cb < 256; cb += 16) {
        const int c = cb + ci;
        const size_t a = baseIn + (size_t)c * HW + (h0 + i);
        tile[c][i] = fm[a] + pos[a];
    }
    __syncthreads();
    const size_t baseOut = ((size_t)b * HW + h0) * HIDN;
    #pragma unroll
    for (int j = 0; j < 16; ++j)
        fmp[baseOut + (size_t)j * HIDN + t] = tile[t][j];
}

// ---------------------------------------------------------------------------
// Fused main kernel: 1 block = 1 batch element, 256 threads (thread = channel).
// DIRECT=1 falls back to gathering from fm/pos directly (no workspace).
// ---------------------------------------------------------------------------
template <int DIRECT>
__global__ __launch_bounds__(256) void mdetr_kernel(
    const float* __restrict__ q_in,  const float* __restrict__ refpt,
    const float* __restrict__ fm,    const float* __restrict__ pos,
    const float* __restrict__ fmp,
    const float* __restrict__ offW,  const float* __restrict__ offB,
    const float* __restrict__ uW1,   const float* __restrict__ uB1,
    const float* __restrict__ uW2,   const float* __restrict__ uB2,
    const float* __restrict__ bW1,   const float* __restrict__ bb1,
    const float* __restrict__ bW2,   const float* __restrict__ bb2,
    const float* __restrict__ bW3,   const float* __restrict__ bb3,
    float* __restrict__ out)
{
    const int b = blockIdx.x;
    const int t = threadIdx.x;

    __shared__ __attribute__((aligned(16))) float q_s[HIDN];
    __shared__ __attribute__((aligned(16))) float fused_s[HIDN];
    __shared__ __attribute__((aligned(16))) float hdd_s[HIDN];
    __shared__ float xy_s[NPTS * 2];
    __shared__ int   off_s[NPTS * 4];
    __shared__ float w_s[NPTS * 4];

    q_s[t] = q_in[(size_t)b * HIDN + t];
    const float rpx = refpt[2 * b + 0];
    const float rpy = refpt[2 * b + 1];

    for (int s = 0; s < NSTAGE; ++s) {
        __syncthreads();
        // ---- offset generator: xy = q @ offW[s].T + offB[s]  (72 outputs) ----
        if (t < NPTS * 2) {
            const float4* wrow = (const float4*)(offW + ((size_t)s * 72 + t) * HIDN);
            const float4* q4   = (const float4*)q_s;
            float a0 = 0.f, a1 = 0.f, a2 = 0.f, a3 = 0.f;
            #pragma unroll 8
            for (int k = 0; k < HIDN / 4; ++k) {
                float4 w4 = wrow[k];
                float4 qq = q4[k];
                a0 += w4.x * qq.x; a1 += w4.y * qq.y;
                a2 += w4.z * qq.z; a3 += w4.w * qq.w;
            }
            xy_s[t] = offB[s * 72 + t] + (a0 + a1) + (a2 + a3);
        }
        __syncthreads();
        // ---- point coords -> 4 taps (weights folded with 1/36 mean) ----
        if (t < NPTS) {
            float px = xy_s[2 * t + 0] + rpx;
            float py = xy_s[2 * t + 1] + rpy;
            // grid=2p-1 ; x=(grid+1)*W/2-0.5 = 20p-0.5, border clip
            float x = fminf(fmaxf(px * (float)WID - 0.5f, 0.f), (float)(WID - 1));
            float y = fminf(fmaxf(py * (float)HGT - 0.5f, 0.f), (float)(HGT - 1));
            float x0f = floorf(x), y0f = floorf(y);
            float wx = x - x0f,   wy = y - y0f;
            int x0 = (int)x0f, y0 = (int)y0f;
            int x1 = min(x0 + 1, WID - 1), y1 = min(y0 + 1, HGT - 1);
            const float inv = 1.f / (float)NPTS;
            w_s[4 * t + 0] = (1.f - wx) * (1.f - wy) * inv;
            w_s[4 * t + 1] = wx * (1.f - wy) * inv;
            w_s[4 * t + 2] = (1.f - wx) * wy * inv;
            w_s[4 * t + 3] = wx * wy * inv;
            if (DIRECT) {
                off_s[4 * t + 0] = y0 * WID + x0;
                off_s[4 * t + 1] = y0 * WID + x1;
                off_s[4 * t + 2] = y1 * WID + x0;
                off_s[4 * t + 3] = y1 * WID + x1;
            } else {
                off_s[4 * t + 0] = (y0 * WID + x0) * HIDN;
                off_s[4 * t + 1] = (y0 * WID + x1) * HIDN;
                off_s[4 * t + 2] = (y1 * WID + x0) * HIDN;
                off_s[4 * t + 3] = (y1 * WID + x1) * HIDN;
            }
        }
        __syncthreads();
        // ---- gather + pooled mean: fused[c] ----
        float acc = 0.f;
        if (!DIRECT) {
            const float* base = fmp + (size_t)b * HW * HIDN + t;
            #pragma unroll 6
            for (int p = 0; p < NPTS; ++p) {
                float v0 = base[off_s[4 * p + 0]];
                float v1 = base[off_s[4 * p + 1]];
                float v2 = base[off_s[4 * p + 2]];
                float v3 = base[off_s[4 * p + 3]];
                acc += w_s[4 * p + 0] * v0 + w_s[4 * p + 1] * v1
                     + w_s[4 * p + 2] * v2 + w_s[4 * p + 3] * v3;
            }
        } else {
            const float* basef = fm  + ((size_t)b * HIDN + t) * HW;
            const float* basep = pos + ((size_t)b * HIDN + t) * HW;
            #pragma unroll 6
            for (int p = 0; p < NPTS; ++p) {
                #pragma unroll
                for (int k = 0; k < 4; ++k) {
                    int idx = off_s[4 * p + k];
                    acc += w_s[4 * p + k] * (basef[idx] + basep[idx]);
                }
            }
        }
        fused_s[t] = acc;
        __syncthreads();
        // ---- MLP layer 1: hdd = relu([fused,q] @ uW1[s].T + uB1[s]) ----
        {
            const float4* w1 = (const float4*)(uW1 + ((size_t)s * HIDN + t) * (2 * HIDN));
            const float4* f4 = (const float4*)fused_s;
            const float4* q4 = (const float4*)q_s;
            float a0 = 0.f, a1 = 0.f, a2 = 0.f, a3 = 0.f;
            #pragma unroll 8
            for (int k = 0; k < HIDN / 4; ++k) {
                float4 w4 = w1[k]; float4 c4 = f4[k];
                a0 += w4.x * c4.x; a1 += w4.y * c4.y;
                a2 += w4.z * c4.z; a3 += w4.w * c4.w;
            }
            #pragma unroll 8
            for (int k = 0; k < HIDN / 4; ++k) {
                float4 w4 = w1[HIDN / 4 + k]; float4 c4 = q4[k];
                a0 += w4.x * c4.x; a1 += w4.y * c4.y;
                a2 += w4.z * c4.z; a3 += w4.w * c4.w;
            }
            float h = uB1[s * HIDN + t] + (a0 + a1) + (a2 + a3);
            hdd_s[t] = fmaxf(h, 0.f);
        }
        __syncthreads();
        // ---- MLP layer 2: q = hdd @ uW2[s].T + uB2[s] ----
        {
            const float4* w2 = (const float4*)(uW2 + ((size_t)s * HIDN + t) * HIDN);
            const float4* h4 = (const float4*)hdd_s;
            float a0 = 0.f, a1 = 0.f, a2 = 0.f, a3 = 0.f;
            #pragma unroll 8
            for (int k = 0; k < HIDN / 4; ++k) {
                float4 w4 = w2[k]; float4 c4 = h4[k];
                a0 += w4.x * c4.x; a1 += w4.y * c4.y;
                a2 += w4.z * c4.z; a3 += w4.w * c4.w;
            }
            q_s[t] = uB2[s * HIDN + t] + (a0 + a1) + (a2 + a3);
        }
    }
    __syncthreads();
    // ---- bbox head ----
    {
        const float4* w = (const float4*)(bW1 + (size_t)t * HIDN);
        const float4* q4 = (const float4*)q_s;
        float a0 = 0.f, a1 = 0.f, a2 = 0.f, a3 = 0.f;
        #pragma unroll 8
        for (int k = 0; k < HIDN / 4; ++k) {
            float4 w4 = w[k]; float4 c4 = q4[k];
            a0 += w4.x * c4.x; a1 += w4.y * c4.y;
            a2 += w4.z * c4.z; a3 += w4.w * c4.w;
        }
        hdd_s[t] = fmaxf(bb1[t] + (a0 + a1) + (a2 + a3), 0.f);
    }
    __syncthreads();
    {
        const float4* w = (const float4*)(bW2 + (size_t)t * HIDN);
        const float4* h4 = (const float4*)hdd_s;
        float a0 = 0.f, a1 = 0.f, a2 = 0.f, a3 = 0.f;
        #pragma unroll 8
        for (int k = 0; k < HIDN / 4; ++k) {
            float4 w4 = w[k]; float4 c4 = h4[k];
            a0 += w4.x * c4.x; a1 += w4.y * c4.y;
            a2 += w4.z * c4.z; a3 += w4.w * c4.w;
        }
        fused_s[t] = fmaxf(bb2[t] + (a0 + a1) + (a2 + a3), 0.f);
    }
    __syncthreads();
    if (t < 4) {
        const float* w = bW3 + (size_t)t * HIDN;
        float h = bb3[t];
        #pragma unroll 16
        for (int k = 0; k < HIDN; ++k) h += w[k] * fused_s[k];
        out[(size_t)b * 4 + t] = 1.f / (1.f + expf(-h));
    }
}

// ---------------------------------------------------------------------------
extern "C" void kernel_launch(void* const* d_in, const int* in_sizes, int n_in,
                              void* d_out, int out_size, void* d_ws, size_t ws_size,
                              hipStream_t stream)
{
    const float* q    = (const float*)d_in[0];
    const float* rp   = (const float*)d_in[1];
    const float* fm   = (const float*)d_in[2];
    const float* pos  = (const float*)d_in[3];
    const float* offW = (const float*)d_in[4];
    const float* offB = (const float*)d_in[5];
    const float* uW1  = (const float*)d_in[6];
    const float* uB1  = (const float*)d_in[7];
    const float* uW2  = (const float*)d_in[8];
    const float* uB2  = (const float*)d_in[9];
    const float* bW1  = (const float*)d_in[10];
    const float* bb1  = (const float*)d_in[11];
    const float* bW2  = (const float*)d_in[12];
    const float* bb2  = (const float*)d_in[13];
    const float* bW3  = (const float*)d_in[14];
    const float* bb3  = (const float*)d_in[15];
    float* out = (float*)d_out;

    const size_t need = (size_t)B_SZ * HW * HIDN * sizeof(float);
    if (ws_size >= need) {
        float* fmp = (float*)d_ws;
        prepass_kernel<<<dim3(HW / 16, B_SZ), 256, 0, stream>>>(fm, pos, fmp);
        mdetr_kernel<0><<<B_SZ, 256, 0, stream>>>(
            q, rp, fm, pos, fmp, offW, offB, uW1, uB1, uW2, uB2,
            bW1, bb1, bW2, bb2, bW3, bb3, out);
    } else {
        mdetr_kernel<1><<<B_SZ, 256, 0, stream>>>(
            q, rp, fm, pos, (const float*)fm /*unused*/, offW, offB, uW1, uB1, uW2, uB2,
            bW1, bb1, bW2, bb2, bW3, bb3, out);
    }
}